// Round 6
// baseline (114.301 us; speedup 1.0000x reference)
//
#include <hip/hip_runtime.h>
#include <cstddef>

#define BH 4
#define CH 64
#define OH 64
#define HH 128
#define WW 128
#define KK 9
#define HW (HH * WW)     // 16384

typedef __attribute__((ext_vector_type(8))) short short8;       // 8 bf16
typedef __attribute__((ext_vector_type(4))) float f32x4;        // MFMA acc
typedef __attribute__((ext_vector_type(2))) float f32x2;
typedef __attribute__((ext_vector_type(4))) unsigned int uint4v;
typedef __attribute__((ext_vector_type(4))) unsigned short ushort4v;

__device__ __forceinline__ unsigned short f2bf(float f) {
    unsigned u = __float_as_uint(f);
    u += 0x7fffu + ((u >> 16) & 1u);   // RNE
    return (unsigned short)(u >> 16);
}
__device__ __forceinline__ f32x2 bf2x2(unsigned d) {
    f32x2 r;
    r.x = __uint_as_float(d << 16);
    r.y = __uint_as_float(d & 0xffff0000u);
    return r;
}
__device__ __forceinline__ unsigned pack_bf2(f32x2 v) {
    unsigned u0 = __float_as_uint(v.x);
    u0 += 0x7fffu + ((u0 >> 16) & 1u);
    unsigned u1 = __float_as_uint(v.y);
    u1 += 0x7fffu + ((u1 >> 16) & 1u);
    return __builtin_amdgcn_perm(u1, u0, 0x07060302);
}
__device__ __forceinline__ uint4v combine4(uint4v c00, uint4v c10, uint4v c01, uint4v c11,
                                           float w00, float w10, float w01, float w11) {
    f32x2 W00 = {w00, w00}, W10 = {w10, w10}, W01 = {w01, w01}, W11 = {w11, w11};
    uint4v r;
#pragma unroll
    for (int j = 0; j < 4; ++j) {
        f32x2 s = W00 * bf2x2(c00[j]) + W10 * bf2x2(c10[j])
                + W01 * bf2x2(c01[j]) + W11 * bf2x2(c11[j]);
        r[j] = pack_bf2(s);
    }
    return r;
}

// ---------------------------------------------------------------------------
// Fused prep: blocks 0..1023 transpose x NCHW f32 -> NHWC bf16;
// blocks 1024..1167 pack weight into MFMA B fragments.
// ---------------------------------------------------------------------------
__global__ __launch_bounds__(256) void dcl_prep(const float* __restrict__ x,
                                                const float* __restrict__ wgt,
                                                unsigned short* __restrict__ xt,
                                                unsigned short* __restrict__ wtb) {
    if (blockIdx.x < 1024) {
        __shared__ float tile[64][65];
        int chunk = blockIdx.x;
        int b = chunk >> 8;
        int hw0 = (chunk & 255) * 64;
        int tid = threadIdx.x;          // 0..255
        int tx = tid & 63;
        int ty = tid >> 6;
        const float* xb = x + (size_t)b * CH * HW;
#pragma unroll
        for (int c = ty; c < 64; c += 4)
            tile[c][tx] = xb[(size_t)c * HW + hw0 + tx];
        __syncthreads();
        unsigned short* xtb = xt + ((size_t)b << 20);
        int c4 = (tid & 15) * 4;
        int p0 = tid >> 4;              // 0..15
#pragma unroll
        for (int it = 0; it < 4; ++it) {
            int pxl = p0 + it * 16;
            ushort4v v = { f2bf(tile[c4 + 0][pxl]), f2bf(tile[c4 + 1][pxl]),
                           f2bf(tile[c4 + 2][pxl]), f2bf(tile[c4 + 3][pxl]) };
            *(ushort4v*)(xtb + (size_t)(hw0 + pxl) * CH + c4) = v;
        }
    } else {
        // wpack: lane l of frag (ks,nt) holds B[k][n], k=ks*32+(l>>4)*8+j,
        // n=nt*16+(l&15), k=t*64+c.  addr: wtb[((ks*4+nt)*64+l)*8+j]
        int idx = (blockIdx.x - 1024) * 256 + threadIdx.x;   // 0..36863
        int j  = idx & 7;
        int l  = (idx >> 3) & 63;
        int nt = (idx >> 9) & 3;
        int ks = idx >> 11;
        int k = ks * 32 + ((l >> 4) * 8) + j;
        int n = nt * 16 + (l & 15);
        int c = k & 63;
        int t = k >> 6;
        wtb[idx] = f2bf(wgt[(n * CH + c) * KK + t]);
    }
}

// ---------------------------------------------------------------------------
// Main: block = 8 waves = 128 px (one image row). ALL of B (72 KB) staged to
// LDS once; ONE barrier before the tap loop, ZERO barriers inside it — all
// 72 gather loads across the 9 taps can overlap with each other and with
// MFMA (barrier-drain was the R5 limiter). Epilogue reuses the B area.
// LDS 73728 B -> 2 blocks/CU (16 waves/CU) — R4 showed occupancy is not the
// limiter, request throughput + serialization is.
// ---------------------------------------------------------------------------
#define NW 8
#define B_WORDS 18432                // 73728 B: full B fragment array
#define OSLICE_WORDS 1040            // 16 * 65 (epilogue slice per wave)

__global__ __launch_bounds__(512, 4) void dcl_main(
        const unsigned short* __restrict__ xt,   // [b][h][w][c] bf16
        const float* __restrict__ offset,
        const unsigned short* __restrict__ wtb,  // packed B fragments (72 KB)
        const float* __restrict__ bias,
        float* __restrict__ out) {
    __shared__ int smem[B_WORDS];
    int tid = threadIdx.x;          // 0..511
    int lane = tid & 63;
    int wave = tid >> 6;            // 0..7

    int row = blockIdx.x;           // 0..511 : one image row per block
    int b = row >> 7;
    int y = row & 127;
    int m = lane & 15;
    int quad = lane >> 4;
    int qoff = quad * 16;
    int pm = wave * 16 + m;         // pixel x-coordinate (0..127)

    const char* xtb = (const char*)xt;
    const float* ob = offset + (((size_t)(b * 18)) << 14) + (y << 7) + pm;
    float pxf = (float)pm;
    float pyf = (float)y;

    // ---- stage ALL of B to LDS: 4608 dwordx4 = 9 per thread, exact ----
    {
        const uint4v* bsrc = (const uint4v*)wtb;
        uint4v* bdst = (uint4v*)smem;
#pragma unroll
        for (int r = 0; r < 9; ++r)
            bdst[r * 512 + tid] = bsrc[r * 512 + tid];
    }

    f32x4 acc[4];
#pragma unroll
    for (int i = 0; i < 4; ++i) acc[i] = (f32x4)(0.f);

    const short8* bl = (const short8*)smem;

    __syncthreads();                // B visible; the ONLY pre-epilogue barrier

    // ---- 9 taps, fully unrolled, barrier-free ----
#pragma unroll
    for (int t = 0; t < 9; ++t) {
        float ox = ob[(size_t)(2 * t) << 14];
        float oy = ob[(size_t)(2 * t + 1) << 14];
        float fx = pxf + ox;
        float fy = pyf + oy;
        float x0f = floorf(fx), y0f = floorf(fy);
        float wx1 = fx - x0f, wy1 = fy - y0f;
        float wx0 = 1.0f - wx1, wy0 = 1.0f - wy1;
        int ix0 = (int)x0f, iy0 = (int)y0f;
        int ix1 = ix0 + 1, iy1 = iy0 + 1;
        bool vx0 = (unsigned)ix0 < (unsigned)WW;
        bool vx1 = (unsigned)ix1 < (unsigned)WW;
        bool vy0 = (unsigned)iy0 < (unsigned)HH;
        bool vy1 = (unsigned)iy1 < (unsigned)HH;
        float w00 = (vx0 && vy0) ? wx0 * wy0 : 0.0f;
        float w10 = (vx1 && vy0) ? wx1 * wy0 : 0.0f;
        float w01 = (vx0 && vy1) ? wx0 * wy1 : 0.0f;
        float w11 = (vx1 && vy1) ? wx1 * wy1 : 0.0f;
        int cx0 = min(max(ix0, 0), WW - 1), cx1 = min(max(ix1, 0), WW - 1);
        int cy0 = min(max(iy0, 0), HH - 1), cy1 = min(max(iy1, 0), HH - 1);
        int base = b << 14;
        int o00 = ((base + (cy0 << 7) + cx0) << 7) + qoff;   // 128 B per px
        int o10 = ((base + (cy0 << 7) + cx1) << 7) + qoff;
        int o01 = ((base + (cy1 << 7) + cx0) << 7) + qoff;
        int o11 = ((base + (cy1 << 7) + cx1) << 7) + qoff;

        uint4v c00a = *(const uint4v*)(xtb + o00);
        uint4v c10a = *(const uint4v*)(xtb + o10);
        uint4v c01a = *(const uint4v*)(xtb + o01);
        uint4v c11a = *(const uint4v*)(xtb + o11);
        uint4v c00b = *(const uint4v*)(xtb + o00 + 64);
        uint4v c10b = *(const uint4v*)(xtb + o10 + 64);
        uint4v c01b = *(const uint4v*)(xtb + o01 + 64);
        uint4v c11b = *(const uint4v*)(xtb + o11 + 64);
        uint4v ra = combine4(c00a, c10a, c01a, c11a, w00, w10, w01, w11);
        uint4v rb = combine4(c00b, c10b, c01b, c11b, w00, w10, w01, w11);
        short8 aa = __builtin_bit_cast(short8, ra);
        short8 ab = __builtin_bit_cast(short8, rb);

        int ks = 2 * t;
#pragma unroll
        for (int nt = 0; nt < 4; ++nt)
            acc[nt] = __builtin_amdgcn_mfma_f32_16x16x32_bf16(
                aa, bl[(ks * 4 + nt) * 64 + lane], acc[nt], 0, 0, 0);
#pragma unroll
        for (int nt = 0; nt < 4; ++nt)
            acc[nt] = __builtin_amdgcn_mfma_f32_16x16x32_bf16(
                ab, bl[((ks + 1) * 4 + nt) * 64 + lane], acc[nt], 0, 0, 0);
    }

    // ---- epilogue: C tiles -> LDS (overwrites B area), coalesced store ----
    __syncthreads();
    float* o_w = (float*)smem + wave * OSLICE_WORDS;   // [p_local][o], stride 65
#pragma unroll
    for (int nt = 0; nt < 4; ++nt)
#pragma unroll
        for (int reg = 0; reg < 4; ++reg)
            o_w[(quad * 4 + reg) * 65 + nt * 16 + m] = acc[nt][reg];
    __syncthreads();

    const float* os = (const float*)smem;
#pragma unroll
    for (int j = tid; j < 64 * 128; j += 512) {
        int o = j >> 7;                  // wave-uniform per iteration
        int p = j & 127;
        int w2 = p >> 4, pl = p & 15;
        float v = os[w2 * OSLICE_WORDS + pl * 65 + o] + bias[o];
        out[(((size_t)(b * OH + o)) << 14) + (y << 7) + p] = v;
    }
}

extern "C" void kernel_launch(void* const* d_in, const int* in_sizes, int n_in,
                              void* d_out, int out_size, void* d_ws, size_t ws_size,
                              hipStream_t stream) {
    const float* x      = (const float*)d_in[0];
    const float* offset = (const float*)d_in[1];
    const float* weight = (const float*)d_in[2];
    const float* bias   = (const float*)d_in[3];
    float* out = (float*)d_out;

    unsigned short* xt  = (unsigned short*)d_ws;                           // 8.39 MB
    unsigned short* wtb = (unsigned short*)((char*)d_ws + (size_t)BH * HW * CH * 2);

    dcl_prep<<<1024 + 144, 256, 0, stream>>>(x, weight, xt, wtb);
    dcl_main<<<BH * HH, 512, 0, stream>>>(xt, offset, wtb, bias, out);
}

// Round 7
// 112.243 us; speedup vs baseline: 1.0183x; 1.0183x over previous
//
#include <hip/hip_runtime.h>
#include <cstddef>

#define BH 4
#define CH 64
#define OH 64
#define HH 128
#define WW 128
#define KK 9
#define HW (HH * WW)     // 16384

typedef __attribute__((ext_vector_type(8))) short short8;       // 8 bf16
typedef __attribute__((ext_vector_type(4))) float f32x4;        // MFMA acc
typedef __attribute__((ext_vector_type(2))) float f32x2;
typedef __attribute__((ext_vector_type(4))) unsigned int uint4v;
typedef __attribute__((ext_vector_type(4))) unsigned short ushort4v;

__device__ __forceinline__ unsigned short f2bf(float f) {
    unsigned u = __float_as_uint(f);
    u += 0x7fffu + ((u >> 16) & 1u);   // RNE
    return (unsigned short)(u >> 16);
}
__device__ __forceinline__ f32x2 bf2x2(unsigned d) {
    f32x2 r;
    r.x = __uint_as_float(d << 16);
    r.y = __uint_as_float(d & 0xffff0000u);
    return r;
}
__device__ __forceinline__ unsigned pack_bf2(f32x2 v) {
    unsigned u0 = __float_as_uint(v.x);
    u0 += 0x7fffu + ((u0 >> 16) & 1u);
    unsigned u1 = __float_as_uint(v.y);
    u1 += 0x7fffu + ((u1 >> 16) & 1u);
    return __builtin_amdgcn_perm(u1, u0, 0x07060302);
}
__device__ __forceinline__ uint4v combine4(uint4v c00, uint4v c10, uint4v c01, uint4v c11,
                                           float w00, float w10, float w01, float w11) {
    f32x2 W00 = {w00, w00}, W10 = {w10, w10}, W01 = {w01, w01}, W11 = {w11, w11};
    uint4v r;
#pragma unroll
    for (int j = 0; j < 4; ++j) {
        f32x2 s = W00 * bf2x2(c00[j]) + W10 * bf2x2(c10[j])
                + W01 * bf2x2(c01[j]) + W11 * bf2x2(c11[j]);
        r[j] = pack_bf2(s);
    }
    return r;
}

// ---------------------------------------------------------------------------
// Fused prep: blocks 0..1023 transpose x NCHW f32 -> NHWC bf16;
// blocks 1024..1167 pack weight into MFMA B fragments.
// ---------------------------------------------------------------------------
__global__ __launch_bounds__(256) void dcl_prep(const float* __restrict__ x,
                                                const float* __restrict__ wgt,
                                                unsigned short* __restrict__ xt,
                                                unsigned short* __restrict__ wtb) {
    if (blockIdx.x < 1024) {
        __shared__ float tile[64][65];
        int chunk = blockIdx.x;
        int b = chunk >> 8;
        int hw0 = (chunk & 255) * 64;
        int tid = threadIdx.x;          // 0..255
        int tx = tid & 63;
        int ty = tid >> 6;
        const float* xb = x + (size_t)b * CH * HW;
#pragma unroll
        for (int c = ty; c < 64; c += 4)
            tile[c][tx] = xb[(size_t)c * HW + hw0 + tx];
        __syncthreads();
        unsigned short* xtb = xt + ((size_t)b << 20);
        int c4 = (tid & 15) * 4;
        int p0 = tid >> 4;              // 0..15
#pragma unroll
        for (int it = 0; it < 4; ++it) {
            int pxl = p0 + it * 16;
            ushort4v v = { f2bf(tile[c4 + 0][pxl]), f2bf(tile[c4 + 1][pxl]),
                           f2bf(tile[c4 + 2][pxl]), f2bf(tile[c4 + 3][pxl]) };
            *(ushort4v*)(xtb + (size_t)(hw0 + pxl) * CH + c4) = v;
        }
    } else {
        // wpack: lane l of frag (ks,nt) holds B[k][n], k=ks*32+(l>>4)*8+j,
        // n=nt*16+(l&15), k=t*64+c.  addr: wtb[((ks*4+nt)*64+l)*8+j]
        int idx = (blockIdx.x - 1024) * 256 + threadIdx.x;   // 0..36863
        int j  = idx & 7;
        int l  = (idx >> 3) & 63;
        int nt = (idx >> 9) & 3;
        int ks = idx >> 11;
        int k = ks * 32 + ((l >> 4) * 8) + j;
        int n = nt * 16 + (l & 15);
        int c = k & 63;
        int t = k >> 6;
        wtb[idx] = f2bf(wgt[(n * CH + c) * KK + t]);
    }
}

// ---------------------------------------------------------------------------
// Main: block = 8 waves covering a 16x8 2D PIXEL TILE (wave w = row y0+w,
// 16 px wide). Gather footprint per block ~22px x 14rows x 128B = 39 KB
// (vs 134 KB for the R6 full-row block) -> L1-resident, shared across all
// 8 waves x 9 taps. B (72 KB) staged to LDS once (keeps B streams out of
// L1); ONE barrier before the tap loop; epilogue reuses the B area.
// ---------------------------------------------------------------------------
#define NW 8
#define B_WORDS 18432                // 73728 B: full B fragment array
#define OSLICE_WORDS 1040            // 16 * 65 (epilogue slice per wave)

__global__ __launch_bounds__(512, 4) void dcl_main(
        const unsigned short* __restrict__ xt,   // [b][h][w][c] bf16
        const float* __restrict__ offset,
        const unsigned short* __restrict__ wtb,  // packed B fragments (72 KB)
        const float* __restrict__ bias,
        float* __restrict__ out) {
    __shared__ int smem[B_WORDS];
    int tid = threadIdx.x;          // 0..511
    int lane = tid & 63;
    int wave = tid >> 6;            // 0..7

    // 2D tiling: 8 x-tiles (16 px) x 16 y-tiles (8 rows) per batch image
    int b  = blockIdx.x >> 7;
    int t7 = blockIdx.x & 127;
    int x0 = (t7 & 7) << 4;         // 0,16,...,112
    int y0 = (t7 >> 3) << 3;        // 0,8,...,120
    int m = lane & 15;
    int quad = lane >> 4;
    int qoff = quad * 16;
    int y = y0 + wave;              // this wave's pixel row
    int pm = x0 + m;                // this lane's pixel x

    const char* xtb = (const char*)xt;
    const float* ob = offset + (((size_t)(b * 18)) << 14) + (y << 7) + pm;
    float pxf = (float)pm;
    float pyf = (float)y;

    // ---- preload all 18 offset values (overlaps with B staging) ----
    float oxv[9], oyv[9];
#pragma unroll
    for (int t = 0; t < 9; ++t) {
        oxv[t] = ob[(size_t)(2 * t) << 14];
        oyv[t] = ob[(size_t)(2 * t + 1) << 14];
    }

    // ---- stage ALL of B to LDS: 4608 dwordx4 = 9 per thread, exact ----
    {
        const uint4v* bsrc = (const uint4v*)wtb;
        uint4v* bdst = (uint4v*)smem;
#pragma unroll
        for (int r = 0; r < 9; ++r)
            bdst[r * 512 + tid] = bsrc[r * 512 + tid];
    }

    f32x4 acc[4];
#pragma unroll
    for (int i = 0; i < 4; ++i) acc[i] = (f32x4)(0.f);

    const short8* bl = (const short8*)smem;

    __syncthreads();                // B visible; the ONLY pre-epilogue barrier

    // ---- 9 taps, fully unrolled, barrier-free ----
#pragma unroll
    for (int t = 0; t < 9; ++t) {
        float fx = pxf + oxv[t];
        float fy = pyf + oyv[t];
        float x0f = floorf(fx), y0f = floorf(fy);
        float wx1 = fx - x0f, wy1 = fy - y0f;
        float wx0 = 1.0f - wx1, wy0 = 1.0f - wy1;
        int ix0 = (int)x0f, iy0 = (int)y0f;
        int ix1 = ix0 + 1, iy1 = iy0 + 1;
        bool vx0 = (unsigned)ix0 < (unsigned)WW;
        bool vx1 = (unsigned)ix1 < (unsigned)WW;
        bool vy0 = (unsigned)iy0 < (unsigned)HH;
        bool vy1 = (unsigned)iy1 < (unsigned)HH;
        float w00 = (vx0 && vy0) ? wx0 * wy0 : 0.0f;
        float w10 = (vx1 && vy0) ? wx1 * wy0 : 0.0f;
        float w01 = (vx0 && vy1) ? wx0 * wy1 : 0.0f;
        float w11 = (vx1 && vy1) ? wx1 * wy1 : 0.0f;
        int cx0 = min(max(ix0, 0), WW - 1), cx1 = min(max(ix1, 0), WW - 1);
        int cy0 = min(max(iy0, 0), HH - 1), cy1 = min(max(iy1, 0), HH - 1);
        int base = b << 14;
        int o00 = ((base + (cy0 << 7) + cx0) << 7) + qoff;   // 128 B per px
        int o10 = ((base + (cy0 << 7) + cx1) << 7) + qoff;
        int o01 = ((base + (cy1 << 7) + cx0) << 7) + qoff;
        int o11 = ((base + (cy1 << 7) + cx1) << 7) + qoff;

        uint4v c00a = *(const uint4v*)(xtb + o00);
        uint4v c10a = *(const uint4v*)(xtb + o10);
        uint4v c01a = *(const uint4v*)(xtb + o01);
        uint4v c11a = *(const uint4v*)(xtb + o11);
        uint4v c00b = *(const uint4v*)(xtb + o00 + 64);
        uint4v c10b = *(const uint4v*)(xtb + o10 + 64);
        uint4v c01b = *(const uint4v*)(xtb + o01 + 64);
        uint4v c11b = *(const uint4v*)(xtb + o11 + 64);
        uint4v ra = combine4(c00a, c10a, c01a, c11a, w00, w10, w01, w11);
        uint4v rb = combine4(c00b, c10b, c01b, c11b, w00, w10, w01, w11);
        short8 aa = __builtin_bit_cast(short8, ra);
        short8 ab = __builtin_bit_cast(short8, rb);

        int ks = 2 * t;
#pragma unroll
        for (int nt = 0; nt < 4; ++nt)
            acc[nt] = __builtin_amdgcn_mfma_f32_16x16x32_bf16(
                aa, bl[(ks * 4 + nt) * 64 + lane], acc[nt], 0, 0, 0);
#pragma unroll
        for (int nt = 0; nt < 4; ++nt)
            acc[nt] = __builtin_amdgcn_mfma_f32_16x16x32_bf16(
                ab, bl[((ks + 1) * 4 + nt) * 64 + lane], acc[nt], 0, 0, 0);
    }

    // ---- epilogue: C tiles -> LDS (overwrites B area), coalesced store ----
    __syncthreads();
    float* o_w = (float*)smem + wave * OSLICE_WORDS;   // [x_local][o], stride 65
#pragma unroll
    for (int nt = 0; nt < 4; ++nt)
#pragma unroll
        for (int reg = 0; reg < 4; ++reg)
            o_w[(quad * 4 + reg) * 65 + nt * 16 + m] = acc[nt][reg];
    __syncthreads();

    const float* os = (const float*)smem;
#pragma unroll
    for (int j = tid; j < 64 * 128; j += 512) {
        int o = j >> 7;                  // wave-uniform per iteration
        int p = j & 127;
        int row = p >> 4, xx = p & 15;   // row selects the wave slice
        float v = os[row * OSLICE_WORDS + xx * 65 + o] + bias[o];
        out[(((size_t)(b * OH + o)) << 14) + ((y0 + row) << 7) + x0 + xx] = v;
    }
}

extern "C" void kernel_launch(void* const* d_in, const int* in_sizes, int n_in,
                              void* d_out, int out_size, void* d_ws, size_t ws_size,
                              hipStream_t stream) {
    const float* x      = (const float*)d_in[0];
    const float* offset = (const float*)d_in[1];
    const float* weight = (const float*)d_in[2];
    const float* bias   = (const float*)d_in[3];
    float* out = (float*)d_out;

    unsigned short* xt  = (unsigned short*)d_ws;                           // 8.39 MB
    unsigned short* wtb = (unsigned short*)((char*)d_ws + (size_t)BH * HW * CH * 2);

    dcl_prep<<<1024 + 144, 256, 0, stream>>>(x, weight, xt, wtb);
    dcl_main<<<BH * HH, 512, 0, stream>>>(xt, offset, wtb, bias, out);
}